// Round 16
// baseline (358.414 us; speedup 1.0000x reference)
//
#include <hip/hip_runtime.h>
#include <hip/hip_bf16.h>
#include <hip/hip_cooperative_groups.h>

namespace cg = cooperative_groups;

#define N_ATOMS 4096
#define NSLAB 32
#define KSTEPS_TOTAL 27
typedef unsigned long long ull;
typedef __attribute__((ext_vector_type(8))) __bf16 bf16x8;
typedef __attribute__((ext_vector_type(4))) float f32x4;
typedef __attribute__((ext_vector_type(8))) unsigned short u16x8;

__device__ __forceinline__ float wrapr(float d, float box, float rbox) {
    return d - box * rintf(d * rbox);
}

__device__ __forceinline__ float ftanh(float x) {
    float t = __expf(2.0f * x);
    return 1.0f - 2.0f * __builtin_amdgcn_rcpf(t + 1.0f);
}

// Single cooperative kernel: P0 zero+weight-pack | P1 slab count | P2 scan+
// scatter | P3 select (8192 tasks) | P4 MLP (1024 tasks). grid.sync between.
__global__ __launch_bounds__(256) void mega_kernel(
    const float* __restrict__ xyz, const float* __restrict__ box,
    const int* __restrict__ types,
    const float* __restrict__ w1, const float* __restrict__ b1,
    const float* __restrict__ w2, const float* __restrict__ b2,
    const float* __restrict__ w3, const float* __restrict__ b3,
    const float* __restrict__ w4, const float* __restrict__ b4,
    float* __restrict__ out,
    int* __restrict__ slabCnt, int* __restrict__ slabFill,
    int* __restrict__ cnt, int* __restrict__ slabOffG,
    int* __restrict__ posArr, int* __restrict__ lists,
    float4* __restrict__ packed,
    float* __restrict__ lfD, int* __restrict__ lfJ,
    float* __restrict__ aX, float* __restrict__ aD,
    __hip_bfloat16* __restrict__ descB, __hip_bfloat16* __restrict__ Wp)
{
    cg::grid_group grid = cg::this_grid();
    const int tid = threadIdx.x;
    const int bid = blockIdx.x;
    const int nb  = gridDim.x;

    // LDS (union of all phases' needs; ~32KB total)
    __shared__ ull sortedk[512];
    __shared__ int hist[256];
    __shared__ int curs[256];
    __shared__ int basev[256];
    __shared__ int wsum[4];
    __shared__ int soff[2 * (NSLAB + 1)];
    __shared__ __hip_bfloat16 Dld[16 * 360];
    __shared__ __hip_bfloat16 Hld[16 * 264];
    __shared__ float b1s[256], b2s[256], b3s[256], w4s[256];
    __shared__ float red[4][16];
    __shared__ float Am[8][12];
    __shared__ int atoms[8];

    const float bx = box[0], by = box[1], bz = box[2];
    const float rbx = 1.0f/bx, rby = 1.0f/by, rbz = 1.0f/bz;

    // ---------------- P0: zero counters + d_out; pack weights ----------------
    if (bid == 0) {
        if (tid < 128) slabCnt[tid] = 0;   // slabCnt[64] + slabFill[64] contiguous
        if (tid == 0) out[0] = 0.0f;
    }
    for (int c = bid; c < 1728; c += nb) {          // 2*864*256 / 256
        int idx = c * 256 + tid;
        int n = idx & 255;
        int k = (idx >> 8) % 864;
        int t = idx / (864 * 256);
        int ksg, kr; float v;
        if (k < 352)      { kr = k;       ksg = kr >> 5;        v = w1[((size_t)t*352 + kr)*256 + n]; }
        else if (k < 608) { kr = k - 352; ksg = 11 + (kr >> 5); v = w2[((size_t)t*256 + kr)*256 + n]; }
        else              { kr = k - 608; ksg = 19 + (kr >> 5); v = w3[((size_t)t*256 + kr)*256 + n]; }
        int l  = (((kr & 31) >> 3) << 4) | (n & 15);
        int e  = kr & 7;
        int nt = n >> 4;
        size_t dst = ((((size_t)t*KSTEPS_TOTAL + ksg)*16 + nt) << 9) + (l << 3) + e;
        Wp[dst] = __float2bfloat16(v);
    }
    grid.sync();

    // ---------------- P1: per-(type,slab) atom counting ----------------
    for (int c = bid; c < 16; c += nb) {
        int i = c * 256 + tid;
        int t = types[i];
        int slab = min(NSLAB - 1, (int)(xyz[3*i+2] * (NSLAB / 40.0f)));
        atomicAdd(&slabCnt[t * NSLAB + slab], 1);
    }
    grid.sync();

    // ---------------- P2: scan + slab-ordered scatter ----------------
    for (int c = bid; c < 16; c += nb) {
        if (tid < 64) {
            int cc = slabCnt[tid];
            int v = cc;
            #pragma unroll
            for (int off = 1; off < 32; off <<= 1) {
                int u = __shfl_up(v, off);
                if ((tid & 31) >= off) v += u;
            }
            int t = tid >> 5, s = tid & 31;
            soff[t * (NSLAB + 1) + s + 1] = v;
            if (s == 0) soff[t * (NSLAB + 1)] = 0;
            if (c == 0) {
                slabOffG[t * (NSLAB + 1) + s + 1] = v;
                if (s == 0)  slabOffG[t * (NSLAB + 1)] = 0;
                if (s == 31) cnt[t] = v;
            }
        }
        __syncthreads();
        int i = c * 256 + tid;
        int t = types[i];
        float z = xyz[3*i+2];
        int slab = min(NSLAB - 1, (int)(z * (NSLAB / 40.0f)));
        int p = atomicAdd(&slabFill[t * NSLAB + slab], 1);
        int idx = soff[t * (NSLAB + 1) + slab] + p;
        lists[t * N_ATOMS + idx] = i;
        posArr[i] = idx;
        packed[t * N_ATOMS + idx] = make_float4(xyz[3*i+0], xyz[3*i+1], z,
                                                __uint_as_float((unsigned)i));
        __syncthreads();
    }
    grid.sync();

    // ---------------- P3: select (task = (atom, type)) ----------------
    for (int task = bid; task < 2 * N_ATOMS; task += nb) {
        const int i = task >> 1;
        const int t = task & 1;
        const int n = cnt[t];
        const float xi = xyz[3*i+0], yi = xyz[3*i+1], zi = xyz[3*i+2];
        const unsigned ibits = (unsigned)i;
        const float4* pk = packed + t * N_ATOMS;
        const int* so = slabOffG + t * (NSLAB + 1);

        float T = __powf(47.75f * bx * by * bz / (float)n, 0.6666667f);
        float Twin = -1.0f, scale = 1.0f;
        int A = 0, L = n;
        int count = 0;
        float d2r[10];

        for (int attempt = 0; attempt < 8; ++attempt) {
            if (T > Twin) {
                float r = sqrtf(T);
                int slo = (int)floorf((zi - r) * (NSLAB / 40.0f)) - 1;
                int shi = (int)floorf((zi + r) * (NSLAB / 40.0f)) + 1;
                int nsl = shi - slo + 1;
                if (nsl >= NSLAB) { A = 0; L = n; }
                else {
                    int ss = slo & (NSLAB - 1);
                    A = so[ss];
                    int send = ss + nsl;
                    L = (send <= NSLAB) ? (so[send] - A)
                                        : (n - A) + so[send - NSLAB];
                }
                Twin = T;
                scale = 256.0f / Twin;
                #pragma unroll
                for (int c = 0; c < 10; ++c) {
                    d2r[c] = __builtin_inff();
                    if ((c << 8) < L) {
                        int m = tid + (c << 8);
                        if (m < L) {
                            int idx = A + m; if (idx >= n) idx -= n;
                            float4 p = pk[idx];
                            if (__float_as_uint(p.w) != ibits) {
                                float ax_ = fabsf(xi - p.x);
                                float ay_ = fabsf(yi - p.y);
                                float az_ = fabsf(zi - p.z);
                                float mx = fminf(ax_, bx - ax_);
                                float my = fminf(ay_, by - ay_);
                                float mz = fminf(az_, bz - az_);
                                d2r[c] = mx*mx + my*my + mz*mz;
                            }
                        }
                    }
                }
            }

            hist[tid] = 0;
            curs[tid] = 0;
            __syncthreads();
            #pragma unroll
            for (int c = 0; c < 10; ++c) {
                if (d2r[c] < T)
                    atomicAdd(&hist[min(255, (int)(d2r[c] * scale))], 1);
            }
            __syncthreads();
            int h = hist[tid];
            int v = h;
            #pragma unroll
            for (int off = 1; off < 64; off <<= 1) {
                int u = __shfl_up(v, off);
                if ((tid & 63) >= off) v += u;
            }
            if ((tid & 63) == 63) wsum[tid >> 6] = v;
            __syncthreads();
            int woff = 0;
            #pragma unroll
            for (int w2 = 0; w2 < 3; ++w2) if (w2 < (tid >> 6)) woff += wsum[w2];
            basev[tid] = v + woff - h;
            count = wsum[0] + wsum[1] + wsum[2] + wsum[3];
            __syncthreads();
            if (count >= 128 && count <= 511) break;
            T *= (count < 128) ? 1.9f : 0.6f;
        }

        #pragma unroll
        for (int c = 0; c < 10; ++c) {
            if (d2r[c] < T) {
                int b = min(255, (int)(d2r[c] * scale));
                int pp = basev[b] + atomicAdd(&curs[b], 1);
                if (pp < 512) {
                    int m = tid + (c << 8);
                    int idx = A + m; if (idx >= n) idx -= n;
                    unsigned j = __float_as_uint(pk[idx].w);
                    sortedk[pp] = ((ull)__float_as_uint(d2r[c]) << 12) | j;
                }
            }
        }
        __syncthreads();
        const int cnt2 = min(count, 512);

        const int ti = types[i];
        const int pi = posArr[i];
        __hip_bfloat16* drow = descB + ((size_t)ti * N_ATOMS + pi) * 256;
        for (int s = tid; s < cnt2; s += 256) {
            ull k = sortedk[s];
            float d2 = __uint_as_float((unsigned)(k >> 12));
            int b = min(255, (int)(d2 * scale));
            int hh = hist[b];
            int r = s;
            if (hh > 1) {
                int bs = basev[b];
                int hi2 = min(bs + hh, cnt2);
                r = bs;
                for (int x = bs; x < hi2; ++x) r += (sortedk[x] < k) ? 1 : 0;
            }
            if (r < 128) {
                int j = (int)(k & 0xFFF);
                float dist = sqrtf(d2);
                drow[t * 128 + r] = __float2bfloat16(1.0f / (dist + 1e-16f));
                if (r < 16) {
                    float dx = wrapr(xi - xyz[3*j+0], bx, rbx);
                    float dy = wrapr(yi - xyz[3*j+1], by, rby);
                    float dz = wrapr(zi - xyz[3*j+2], bz, rbz);
                    int s2 = i * 32 + t * 16 + r;
                    aX[3*s2+0] = dx; aX[3*s2+1] = dy; aX[3*s2+2] = dz;
                    aD[s2] = dist;
                }
                if (r < 2) {
                    lfD[i * 4 + t * 2 + r] = dist;
                    lfJ[i * 4 + t * 2 + r] = j;
                }
            }
        }
        __syncthreads();   // protect sortedk/hist/basev across task iterations
    }
    grid.sync();

    // ---------------- P4: MLP (task = (type, 8-atom blk)) ----------------
    const int w   = tid >> 6;
    const int l   = tid & 63;
    const int lane15 = l & 15;

    for (int task = bid; task < 1024; task += nb) {
        const int t   = task >> 9;
        const int blk = task & 511;
        const int n_t = cnt[t];
        const int p0  = blk * 8;
        if (p0 >= n_t) continue;
        const int nv  = min(8, n_t - p0);

        b1s[tid] = b1[t * 256 + tid];
        b2s[tid] = b2[t * 256 + tid];
        b3s[tid] = b3[t * 256 + tid];
        w4s[tid] = w4[t * 256 + tid];
        if (tid < 8)
            atoms[tid] = (tid < nv) ? lists[t * N_ATOMS + p0 + tid] : -1;

        for (int c = tid; c < 16 * 44; c += 256) {
            int row = c / 44, kc = c - row * 44;
            u16x8 v = {0,0,0,0,0,0,0,0};
            if (row < nv && kc < 32)
                v = *(const u16x8*)&descB[((size_t)t*N_ATOMS + p0 + row)*256 + kc*8];
            *(u16x8*)&Dld[row * 360 + kc * 8] = v;
        }
        __syncthreads();

        if (tid < 8 && atoms[tid] >= 0) {
            const int a = atoms[tid];
            const float xi = xyz[3*a+0], yi = xyz[3*a+1], zi = xyz[3*a+2];
            float cd[4]; int cj[4];
            #pragma unroll
            for (int c = 0; c < 4; ++c) { cd[c] = lfD[a*4+c]; cj[c] = lfJ[a*4+c]; }
            int i0 = 0; float bm = cd[0];
            for (int c = 1; c < 4; ++c) if (cd[c] < bm) { bm = cd[c]; i0 = c; }
            int i1 = -1; float b1v = 3.4e38f;
            for (int c = 0; c < 4; ++c) { if (c == i0) continue; if (cd[c] < b1v) { b1v = cd[c]; i1 = c; } }

            int ja = cj[i0], jb = cj[i1];
            float da = cd[i0], db = cd[i1];
            float r0x = wrapr(xi - xyz[3*ja+0], bx, rbx) / (da + 1e-16f);
            float r0y = wrapr(yi - xyz[3*ja+1], by, rby) / (da + 1e-16f);
            float r0z = wrapr(zi - xyz[3*ja+2], bz, rbz) / (da + 1e-16f);
            float r1x = wrapr(xi - xyz[3*jb+0], bx, rbx) / (db + 1e-16f);
            float r1y = wrapr(yi - xyz[3*jb+1], by, rby) / (db + 1e-16f);
            float r1z = wrapr(zi - xyz[3*jb+2], bz, rbz) / (db + 1e-16f);
            float dot = r0x*r1x + r0y*r1y + r0z*r1z;
            float v2x = r1x - dot*r0x, v2y = r1y - dot*r0y, v2z = r1z - dot*r0z;
            float n2 = sqrtf(v2x*v2x + v2y*v2y + v2z*v2z);
            v2x /= n2; v2y /= n2; v2z /= n2;
            float v3x = r0y*r1z - r0z*r1y;
            float v3y = r0z*r1x - r0x*r1z;
            float v3z = r0x*r1y - r0y*r1x;
            float n3 = sqrtf(v3x*v3x + v3y*v3y + v3z*v3z);
            v3x /= n3; v3y /= n3; v3z /= n3;
            Am[tid][0]=r0x; Am[tid][1]=r0y; Am[tid][2]=r0z;
            Am[tid][3]=v2x; Am[tid][4]=v2y; Am[tid][5]=v2z;
            Am[tid][6]=v3x; Am[tid][7]=v3y; Am[tid][8]=v3z;
        }
        __syncthreads();

        if (tid < 128) {
            const int q = tid >> 4, s = tid & 15;
            const int a = atoms[q];
            if (a >= 0) {
                #pragma unroll
                for (int half = 0; half < 2; ++half) {
                    int ss = s + (half << 4);
                    int sidx = a * 32 + ss;
                    float d  = aD[sidx];
                    float dn = d + 1e-16f;
                    float ax = aX[3*sidx+0] / dn;
                    float ay = aX[3*sidx+1] / dn;
                    float az = aX[3*sidx+2] / dn;
                    float o0 = (Am[q][0]*ax + Am[q][1]*ay + Am[q][2]*az) / dn;
                    float o1 = (Am[q][3]*ax + Am[q][4]*ay + Am[q][5]*az) / dn;
                    float o2 = (Am[q][6]*ax + Am[q][7]*ay + Am[q][8]*az) / dn;
                    Dld[q*360 + 256 + 3*ss + 0] = __float2bfloat16(o0);
                    Dld[q*360 + 256 + 3*ss + 1] = __float2bfloat16(o1);
                    Dld[q*360 + 256 + 3*ss + 2] = __float2bfloat16(o2);
                }
            }
        }
        __syncthreads();

        const __hip_bfloat16* wpt = Wp + (((size_t)t * KSTEPS_TOTAL * 16 + (w << 2)) << 9);
        const int aoff = ((l >> 4) << 3);
        const int rb   = ((l >> 4) << 2);

        f32x4 acc0 = {0,0,0,0}, acc1 = {0,0,0,0}, acc2 = {0,0,0,0}, acc3 = {0,0,0,0};

#define KSTEP(SRC, STRIDE, KSG) { \
    bf16x8 a = *(const bf16x8*)&SRC[lane15 * STRIDE + (ks << 5) + aoff]; \
    const __hip_bfloat16* wk = wpt + (((size_t)(KSG) << 13)) + (l << 3); \
    bf16x8 bv0 = *(const bf16x8*)(wk); \
    bf16x8 bv1 = *(const bf16x8*)(wk + 512); \
    bf16x8 bv2 = *(const bf16x8*)(wk + 1024); \
    bf16x8 bv3 = *(const bf16x8*)(wk + 1536); \
    acc0 = __builtin_amdgcn_mfma_f32_16x16x32_bf16(a, bv0, acc0, 0, 0, 0); \
    acc1 = __builtin_amdgcn_mfma_f32_16x16x32_bf16(a, bv1, acc1, 0, 0, 0); \
    acc2 = __builtin_amdgcn_mfma_f32_16x16x32_bf16(a, bv2, acc2, 0, 0, 0); \
    acc3 = __builtin_amdgcn_mfma_f32_16x16x32_bf16(a, bv3, acc3, 0, 0, 0); }

#define STORE_H(ACC, NT, DST, STRIDE, BS) if (rb < nv) { \
    int n = (w << 6) + ((NT) << 4) + lane15; \
    float bb = BS[n]; \
    DST[(rb + 0) * STRIDE + n] = __float2bfloat16(ftanh(ACC[0] + bb)); \
    DST[(rb + 1) * STRIDE + n] = __float2bfloat16(ftanh(ACC[1] + bb)); \
    DST[(rb + 2) * STRIDE + n] = __float2bfloat16(ftanh(ACC[2] + bb)); \
    DST[(rb + 3) * STRIDE + n] = __float2bfloat16(ftanh(ACC[3] + bb)); }

        #pragma unroll 2
        for (int ks = 0; ks < 11; ++ks) KSTEP(Dld, 360, ks)
        STORE_H(acc0, 0, Hld, 264, b1s)
        STORE_H(acc1, 1, Hld, 264, b1s)
        STORE_H(acc2, 2, Hld, 264, b1s)
        STORE_H(acc3, 3, Hld, 264, b1s)
        __syncthreads();

        acc0 = (f32x4){0,0,0,0}; acc1 = acc0; acc2 = acc0; acc3 = acc0;
        #pragma unroll 2
        for (int ks = 0; ks < 8; ++ks) KSTEP(Hld, 264, 11 + ks)
        __syncthreads();
        STORE_H(acc0, 0, Dld, 360, b2s)
        STORE_H(acc1, 1, Dld, 360, b2s)
        STORE_H(acc2, 2, Dld, 360, b2s)
        STORE_H(acc3, 3, Dld, 360, b2s)
        __syncthreads();

        acc0 = (f32x4){0,0,0,0}; acc1 = acc0; acc2 = acc0; acc3 = acc0;
        #pragma unroll 2
        for (int ks = 0; ks < 8; ++ks) KSTEP(Dld, 360, 19 + ks)

        float s0 = 0.f, s1 = 0.f, s2 = 0.f, s3 = 0.f;
#define EPART(ACC, NT) if (rb < nv) { \
    int n = (w << 6) + ((NT) << 4) + lane15; \
    float wv = w4s[n]; float bb = b3s[n]; \
    s0 += ftanh(ACC[0] + bb) * wv; s1 += ftanh(ACC[1] + bb) * wv; \
    s2 += ftanh(ACC[2] + bb) * wv; s3 += ftanh(ACC[3] + bb) * wv; }
        EPART(acc0, 0) EPART(acc1, 1) EPART(acc2, 2) EPART(acc3, 3)

        #pragma unroll
        for (int off = 1; off <= 8; off <<= 1) {
            s0 += __shfl_xor(s0, off);
            s1 += __shfl_xor(s1, off);
            s2 += __shfl_xor(s2, off);
            s3 += __shfl_xor(s3, off);
        }
        if (lane15 == 0) {
            red[w][rb + 0] = s0;
            red[w][rb + 1] = s1;
            red[w][rb + 2] = s2;
            red[w][rb + 3] = s3;
        }
        __syncthreads();

        if (tid < 16) {
            float e = red[0][tid] + red[1][tid] + red[2][tid] + red[3][tid];
            e = (tid < nv) ? (e + b4[t]) : 0.0f;
            #pragma unroll
            for (int off = 1; off <= 8; off <<= 1) e += __shfl_xor(e, off);
            if (tid == 0) atomicAdd(out, e);
        }
        __syncthreads();   // protect LDS across task iterations
#undef KSTEP
#undef STORE_H
#undef EPART
    }
}

extern "C" void kernel_launch(void* const* d_in, const int* in_sizes, int n_in,
                              void* d_out, int out_size, void* d_ws, size_t ws_size,
                              hipStream_t stream) {
    const float* xyz   = (const float*)d_in[0];
    const float* box   = (const float*)d_in[1];
    const int*   types = (const int*)  d_in[2];
    const float* w1 = (const float*)d_in[3];
    const float* b1 = (const float*)d_in[4];
    const float* w2 = (const float*)d_in[5];
    const float* b2 = (const float*)d_in[6];
    const float* w3 = (const float*)d_in[7];
    const float* b3 = (const float*)d_in[8];
    const float* w4 = (const float*)d_in[9];
    const float* b4 = (const float*)d_in[10];
    float* out = (float*)d_out;

    // workspace (4B units; 16B alignment preserved at packed/descB)
    float* p = (float*)d_ws;
    int*    slabCnt  = (int*)p;        p += 64;
    int*    slabFill = (int*)p;        p += 64;
    int*    cnt      = (int*)p;        p += 16;
    int*    slabOffG = (int*)p;        p += 68;
    int*    posArr   = (int*)p;        p += N_ATOMS;
    int*    lists    = (int*)p;        p += 2 * N_ATOMS;
    float4* packed   = (float4*)p;     p += 2 * N_ATOMS * 4;
    float*  lfD      = p;              p += 4 * N_ATOMS;
    int*    lfJ      = (int*)p;        p += 4 * N_ATOMS;
    float*  aX       = p;              p += 96 * N_ATOMS;
    float*  aD       = p;              p += 32 * N_ATOMS;
    __hip_bfloat16* descB = (__hip_bfloat16*)p;
    p += (size_t)2 * N_ATOMS * 256 / 2;
    __hip_bfloat16* Wp = (__hip_bfloat16*)p;
    p += (size_t)2 * KSTEPS_TOTAL * 16 * 512 / 2;

    // size grid to guaranteed co-residency
    int perCU = 0;
    hipOccupancyMaxActiveBlocksPerMultiprocessor(&perCU, mega_kernel, 256, 0);
    if (perCU < 1) perCU = 1;
    int grid = perCU * 256;                 // MI355X: 256 CUs
    if (grid > 2048) grid = 2048;
    if (grid < 64)   grid = 64;

    void* args[] = {
        (void*)&xyz, (void*)&box, (void*)&types,
        (void*)&w1, (void*)&b1, (void*)&w2, (void*)&b2,
        (void*)&w3, (void*)&b3, (void*)&w4, (void*)&b4,
        (void*)&out,
        (void*)&slabCnt, (void*)&slabFill, (void*)&cnt, (void*)&slabOffG,
        (void*)&posArr, (void*)&lists, (void*)&packed,
        (void*)&lfD, (void*)&lfJ, (void*)&aX, (void*)&aD,
        (void*)&descB, (void*)&Wp
    };
    hipLaunchCooperativeKernel((const void*)mega_kernel, dim3(grid), dim3(256),
                               args, 0, stream);
}

// Round 17
// 70.306 us; speedup vs baseline: 5.0979x; 5.0979x over previous
//
#include <hip/hip_runtime.h>
#include <hip/hip_bf16.h>

#define N_ATOMS 4096
#define NSLAB 32
#define PSTRIDE 8192   // per-type packed stride (duplicated window)
#define KSTEPS_TOTAL 27
typedef unsigned long long ull;
typedef __attribute__((ext_vector_type(8))) __bf16 bf16x8;
typedef __attribute__((ext_vector_type(4))) float f32x4;
typedef __attribute__((ext_vector_type(8))) unsigned short u16x8;

__device__ __forceinline__ float wrapr(float d, float box, float rbox) {
    return d - box * rintf(d * rbox);
}

__device__ __forceinline__ float ftanh(float x) {
    float t = __expf(2.0f * x);
    return 1.0f - 2.0f * __builtin_amdgcn_rcpf(t + 1.0f);
}

// blocks 0..15: per-block slab histograms (no global atomics, no pre-zero);
// block 0 zeroes d_out. blocks 16..: bf16 MFMA B-fragment weight packing.
__global__ __launch_bounds__(256) void prep_kernel(
    const float* __restrict__ xyz, const int* __restrict__ types,
    int* __restrict__ histBlk, float* __restrict__ out,
    const float* __restrict__ w1, const float* __restrict__ w2,
    const float* __restrict__ w3, __hip_bfloat16* __restrict__ Wp)
{
    const int bid = blockIdx.x;
    const int tid = threadIdx.x;
    if (bid < 16) {
        __shared__ int lh[64];
        if (tid < 64) lh[tid] = 0;
        __syncthreads();
        int i = bid * 256 + tid;
        if (i == 0) out[0] = 0.0f;
        int t = types[i];
        int slab = min(NSLAB - 1, (int)(xyz[3*i+2] * (NSLAB / 40.0f)));
        atomicAdd(&lh[t * NSLAB + slab], 1);
        __syncthreads();
        if (tid < 64) histBlk[bid * 64 + tid] = lh[tid];
    } else {
        int idx = (bid - 16) * 256 + tid;   // exactly 2*864*256 threads
        int n = idx & 255;
        int k = (idx >> 8) % 864;
        int t = idx / (864 * 256);
        int ksg, kr; float v;
        if (k < 352)      { kr = k;       ksg = kr >> 5;        v = w1[((size_t)t*352 + kr)*256 + n]; }
        else if (k < 608) { kr = k - 352; ksg = 11 + (kr >> 5); v = w2[((size_t)t*256 + kr)*256 + n]; }
        else              { kr = k - 608; ksg = 19 + (kr >> 5); v = w3[((size_t)t*256 + kr)*256 + n]; }
        int l  = (((kr & 31) >> 3) << 4) | (n & 15);
        int e  = kr & 7;
        int nt = n >> 4;
        size_t dst = ((((size_t)t*KSTEPS_TOTAL + ksg)*16 + nt) << 9) + (l << 3) + e;
        Wp[dst] = __float2bfloat16(v);
    }
}

// 16 blocks: cross-block bases from histBlk + segmented scan -> slab-ordered
// scatter; packed written duplicated ([idx] and [idx+n]) for wrap-free windows.
__global__ __launch_bounds__(256) void fill_kernel(
    const float* __restrict__ xyz, const int* __restrict__ types,
    const int* __restrict__ histBlk,
    int* __restrict__ slabOffG, int* __restrict__ cntG,
    int* __restrict__ lists, int* __restrict__ posArr,
    float4* __restrict__ packed)
{
    __shared__ int base[64];
    __shared__ int cur[64];
    __shared__ int cntS[2];
    const int tid = threadIdx.x;
    const int bid = blockIdx.x;

    if (tid < 64) {
        int tot = 0, pre = 0;
        #pragma unroll
        for (int b = 0; b < 16; ++b) {
            int h = histBlk[b * 64 + tid];
            tot += h;
            if (b < bid) pre += h;
        }
        int v = tot;   // segmented (32-wide) inclusive scan within 64-lane wave
        #pragma unroll
        for (int off = 1; off < 32; off <<= 1) {
            int u = __shfl_up(v, off);
            if ((tid & 31) >= off) v += u;
        }
        base[tid] = (v - tot) + pre;
        cur[tid]  = 0;
        int t = tid >> 5, s = tid & 31;
        if (s == 31) cntS[t] = v;
        if (bid == 0) {
            slabOffG[t * (NSLAB + 1) + s + 1] = v;
            if (s == 0)  slabOffG[t * (NSLAB + 1)] = 0;
            if (s == 31) cntG[t] = v;
        }
    }
    __syncthreads();

    int i = bid * 256 + tid;
    int t = types[i];
    float z = xyz[3*i+2];
    int slab = min(NSLAB - 1, (int)(z * (NSLAB / 40.0f)));
    int ts = t * NSLAB + slab;
    int idx = base[ts] + atomicAdd(&cur[ts], 1);
    lists[t * N_ATOMS + idx] = i;
    posArr[i] = idx;
    float4 pv = make_float4(xyz[3*i+0], xyz[3*i+1], z, __uint_as_float((unsigned)i));
    packed[t * PSTRIDE + idx] = pv;
    packed[t * PSTRIDE + idx + cntS[t]] = pv;   // duplicate for wrap-free reads
}

// One block per (atom, type): z-slab window (wrap-free via duplicated packed),
// bucket histogram + scan + in-place cursor scatter, exact within-bucket rank
// by 43-bit key (d2bits<<12 | j) -> exact sorted top-128.
__global__ __launch_bounds__(256) void select_kernel(
    const float* __restrict__ xyz, const float* __restrict__ box,
    const int* __restrict__ cnt, const float4* __restrict__ packed,
    const int* __restrict__ slabOffG,
    const int* __restrict__ types, const int* __restrict__ posArr,
    __hip_bfloat16* __restrict__ descB, float* __restrict__ aX,
    float* __restrict__ aD, float* __restrict__ lfD, int* __restrict__ lfJ)
{
    __shared__ ull sortedk[512];
    __shared__ int hist[256];
    __shared__ int basev[256];
    __shared__ int wsum[4];

    const int i   = blockIdx.x >> 1;
    const int t   = blockIdx.x & 1;
    const int tid = threadIdx.x;
    const int n   = cnt[t];
    const float bx = box[0], by = box[1], bz = box[2];
    const float rbx = 1.0f/bx, rby = 1.0f/by, rbz = 1.0f/bz;
    const float xi = xyz[3*i+0], yi = xyz[3*i+1], zi = xyz[3*i+2];
    const unsigned ibits = (unsigned)i;
    const float4* pk = packed + t * PSTRIDE;
    const int* soff = slabOffG + t * (NSLAB + 1);

    float T = __powf(47.75f * bx * by * bz / (float)n, 0.6666667f);
    float Twin = -1.0f, scale = 1.0f;
    int A = 0, L = n;
    int count = 0;
    float d2r[10];

    for (int attempt = 0; attempt < 8; ++attempt) {
        if (T > Twin) {
            float r = sqrtf(T);
            int slo = (int)floorf((zi - r) * (NSLAB / 40.0f)) - 1;
            int shi = (int)floorf((zi + r) * (NSLAB / 40.0f)) + 1;
            int nsl = shi - slo + 1;
            if (nsl >= NSLAB) { A = 0; L = n; }
            else {
                int ss = slo & (NSLAB - 1);
                A = soff[ss];
                int send = ss + nsl;
                L = (send <= NSLAB) ? (soff[send] - A)
                                    : (n - A) + soff[send - NSLAB];
            }
            Twin = T;
            scale = 256.0f / Twin;
            #pragma unroll
            for (int c = 0; c < 10; ++c) {
                d2r[c] = __builtin_inff();
                if ((c << 8) < L) {
                    int m = tid + (c << 8);
                    if (m < L) {
                        float4 p = pk[A + m];           // wrap-free (duplicated)
                        if (__float_as_uint(p.w) != ibits) {
                            float ax_ = fabsf(xi - p.x);
                            float ay_ = fabsf(yi - p.y);
                            float az_ = fabsf(zi - p.z);
                            float mx = fminf(ax_, bx - ax_);
                            float my = fminf(ay_, by - ay_);
                            float mz = fminf(az_, bz - az_);
                            d2r[c] = mx*mx + my*my + mz*mz;
                        }
                    }
                }
            }
        }

        hist[tid] = 0;
        __syncthreads();
        #pragma unroll
        for (int c = 0; c < 10; ++c) {
            if (d2r[c] < T)
                atomicAdd(&hist[min(255, (int)(d2r[c] * scale))], 1);
        }
        __syncthreads();
        int h = hist[tid];
        int v = h;
        #pragma unroll
        for (int off = 1; off < 64; off <<= 1) {
            int u = __shfl_up(v, off);
            if ((tid & 63) >= off) v += u;
        }
        if ((tid & 63) == 63) wsum[tid >> 6] = v;
        __syncthreads();
        int woff = 0;
        #pragma unroll
        for (int w2 = 0; w2 < 3; ++w2) if (w2 < (tid >> 6)) woff += wsum[w2];
        basev[tid] = v + woff - h;     // exclusive start; doubles as cursor
        count = wsum[0] + wsum[1] + wsum[2] + wsum[3];
        __syncthreads();
        if (count >= 128 && count <= 511) break;
        T *= (count < 128) ? 1.9f : 0.6f;
    }

    // scatter (basev[b] is the live cursor; ends at start+hist[b])
    #pragma unroll
    for (int c = 0; c < 10; ++c) {
        if (d2r[c] < T) {
            int b = min(255, (int)(d2r[c] * scale));
            int pp = atomicAdd(&basev[b], 1);
            if (pp < 512) {
                int m = tid + (c << 8);
                unsigned j = __float_as_uint(pk[A + m].w);
                sortedk[pp] = ((ull)__float_as_uint(d2r[c]) << 12) | j;
            }
        }
    }
    __syncthreads();
    const int cnt2 = min(count, 512);

    const int ti = types[i];
    const int pi = posArr[i];
    __hip_bfloat16* drow = descB + ((size_t)ti * N_ATOMS + pi) * 256;
    for (int s = tid; s < cnt2; s += 256) {
        ull k = sortedk[s];
        float d2 = __uint_as_float((unsigned)(k >> 12));
        int b = min(255, (int)(d2 * scale));
        int hh = hist[b];
        int r = s;
        if (hh > 1) {
            int bs = basev[b] - hh;    // cursor end minus bucket size = start
            int hi2 = min(bs + hh, cnt2);
            r = bs;
            for (int x = bs; x < hi2; ++x) r += (sortedk[x] < k) ? 1 : 0;
        }
        if (r < 128) {
            int j = (int)(k & 0xFFF);
            float dist = sqrtf(d2);
            drow[t * 128 + r] = __float2bfloat16(1.0f / (dist + 1e-16f));
            if (r < 16) {
                float dx = wrapr(xi - xyz[3*j+0], bx, rbx);
                float dy = wrapr(yi - xyz[3*j+1], by, rby);
                float dz = wrapr(zi - xyz[3*j+2], bz, rbz);
                int s2 = i * 32 + t * 16 + r;
                aX[3*s2+0] = dx; aX[3*s2+1] = dy; aX[3*s2+2] = dz;
                aD[s2] = dist;
            }
            if (r < 2) {
                lfD[i * 4 + t * 2 + r] = dist;
                lfJ[i * 4 + t * 2 + r] = j;
            }
        }
    }
}

// Fused: local frame + rot features + 3-layer bf16-MFMA MLP + energy.
// Block = 8 atoms x 256 neurons, 4 waves. C/D: col=lane&15, row=(lane>>4)*4+reg.
__global__ __launch_bounds__(256) void mlp_fused_kernel(
    const int* __restrict__ cnt, const int* __restrict__ lists,
    const float* __restrict__ xyz, const float* __restrict__ box,
    const float* __restrict__ aX, const float* __restrict__ aD,
    const float* __restrict__ lfD, const int* __restrict__ lfJ,
    const __hip_bfloat16* __restrict__ descB,
    const __hip_bfloat16* __restrict__ Wp,
    const float* __restrict__ b1, const float* __restrict__ b2,
    const float* __restrict__ b3,
    const float* __restrict__ w4, const float* __restrict__ b4,
    float* __restrict__ out)
{
    __shared__ __hip_bfloat16 Dld[16 * 360];
    __shared__ __hip_bfloat16 Hld[16 * 264];
    __shared__ float b1s[256], b2s[256], b3s[256], w4s[256];
    __shared__ float red[4][16];
    __shared__ float Am[8][12];
    __shared__ int atoms[8];

    const int t   = blockIdx.y;
    const int n_t = cnt[t];
    const int p0  = blockIdx.x * 8;
    if (p0 >= n_t) return;
    const int nv  = min(8, n_t - p0);
    const int tid = threadIdx.x;
    const int w   = tid >> 6;
    const int l   = tid & 63;
    const int lane15 = l & 15;
    const float bx = box[0], by = box[1], bz = box[2];
    const float rbx = 1.0f/bx, rby = 1.0f/by, rbz = 1.0f/bz;

    b1s[tid] = b1[t * 256 + tid];
    b2s[tid] = b2[t * 256 + tid];
    b3s[tid] = b3[t * 256 + tid];
    w4s[tid] = w4[t * 256 + tid];
    if (tid < 8)
        atoms[tid] = (tid < nv) ? lists[t * N_ATOMS + p0 + tid] : -1;

    for (int c = tid; c < 16 * 44; c += 256) {
        int row = c / 44, kc = c - row * 44;
        u16x8 v = {0,0,0,0,0,0,0,0};
        if (row < nv && kc < 32)
            v = *(const u16x8*)&descB[((size_t)t*N_ATOMS + p0 + row)*256 + kc*8];
        *(u16x8*)&Dld[row * 360 + kc * 8] = v;
    }
    __syncthreads();

    if (tid < 8 && atoms[tid] >= 0) {
        const int a = atoms[tid];
        const float xi = xyz[3*a+0], yi = xyz[3*a+1], zi = xyz[3*a+2];
        float cd[4]; int cj[4];
        #pragma unroll
        for (int c = 0; c < 4; ++c) { cd[c] = lfD[a*4+c]; cj[c] = lfJ[a*4+c]; }
        int i0 = 0; float bm = cd[0];
        for (int c = 1; c < 4; ++c) if (cd[c] < bm) { bm = cd[c]; i0 = c; }
        int i1 = -1; float b1v = 3.4e38f;
        for (int c = 0; c < 4; ++c) { if (c == i0) continue; if (cd[c] < b1v) { b1v = cd[c]; i1 = c; } }

        int ja = cj[i0], jb = cj[i1];
        float da = cd[i0], db = cd[i1];
        float r0x = wrapr(xi - xyz[3*ja+0], bx, rbx) / (da + 1e-16f);
        float r0y = wrapr(yi - xyz[3*ja+1], by, rby) / (da + 1e-16f);
        float r0z = wrapr(zi - xyz[3*ja+2], bz, rbz) / (da + 1e-16f);
        float r1x = wrapr(xi - xyz[3*jb+0], bx, rbx) / (db + 1e-16f);
        float r1y = wrapr(yi - xyz[3*jb+1], by, rby) / (db + 1e-16f);
        float r1z = wrapr(zi - xyz[3*jb+2], bz, rbz) / (db + 1e-16f);
        float dot = r0x*r1x + r0y*r1y + r0z*r1z;
        float v2x = r1x - dot*r0x, v2y = r1y - dot*r0y, v2z = r1z - dot*r0z;
        float n2 = sqrtf(v2x*v2x + v2y*v2y + v2z*v2z);
        v2x /= n2; v2y /= n2; v2z /= n2;
        float v3x = r0y*r1z - r0z*r1y;
        float v3y = r0z*r1x - r0x*r1z;
        float v3z = r0x*r1y - r0y*r1x;
        float n3 = sqrtf(v3x*v3x + v3y*v3y + v3z*v3z);
        v3x /= n3; v3y /= n3; v3z /= n3;
        Am[tid][0]=r0x; Am[tid][1]=r0y; Am[tid][2]=r0z;
        Am[tid][3]=v2x; Am[tid][4]=v2y; Am[tid][5]=v2z;
        Am[tid][6]=v3x; Am[tid][7]=v3y; Am[tid][8]=v3z;
    }
    __syncthreads();

    if (tid < 128) {
        const int q = tid >> 4, s = tid & 15;
        const int a = atoms[q];
        if (a >= 0) {
            #pragma unroll
            for (int half = 0; half < 2; ++half) {
                int ss = s + (half << 4);
                int sidx = a * 32 + ss;
                float d  = aD[sidx];
                float dn = d + 1e-16f;
                float ax = aX[3*sidx+0] / dn;
                float ay = aX[3*sidx+1] / dn;
                float az = aX[3*sidx+2] / dn;
                float o0 = (Am[q][0]*ax + Am[q][1]*ay + Am[q][2]*az) / dn;
                float o1 = (Am[q][3]*ax + Am[q][4]*ay + Am[q][5]*az) / dn;
                float o2 = (Am[q][6]*ax + Am[q][7]*ay + Am[q][8]*az) / dn;
                Dld[q*360 + 256 + 3*ss + 0] = __float2bfloat16(o0);
                Dld[q*360 + 256 + 3*ss + 1] = __float2bfloat16(o1);
                Dld[q*360 + 256 + 3*ss + 2] = __float2bfloat16(o2);
            }
        }
    }
    __syncthreads();

    const __hip_bfloat16* wpt = Wp + (((size_t)t * KSTEPS_TOTAL * 16 + (w << 2)) << 9);
    const int aoff = ((l >> 4) << 3);
    const int rb   = ((l >> 4) << 2);

    f32x4 acc0 = {0,0,0,0}, acc1 = {0,0,0,0}, acc2 = {0,0,0,0}, acc3 = {0,0,0,0};

#define KSTEP(SRC, STRIDE, KSG) { \
    bf16x8 a = *(const bf16x8*)&SRC[lane15 * STRIDE + (ks << 5) + aoff]; \
    const __hip_bfloat16* wk = wpt + (((size_t)(KSG) << 13)) + (l << 3); \
    bf16x8 bv0 = *(const bf16x8*)(wk); \
    bf16x8 bv1 = *(const bf16x8*)(wk + 512); \
    bf16x8 bv2 = *(const bf16x8*)(wk + 1024); \
    bf16x8 bv3 = *(const bf16x8*)(wk + 1536); \
    acc0 = __builtin_amdgcn_mfma_f32_16x16x32_bf16(a, bv0, acc0, 0, 0, 0); \
    acc1 = __builtin_amdgcn_mfma_f32_16x16x32_bf16(a, bv1, acc1, 0, 0, 0); \
    acc2 = __builtin_amdgcn_mfma_f32_16x16x32_bf16(a, bv2, acc2, 0, 0, 0); \
    acc3 = __builtin_amdgcn_mfma_f32_16x16x32_bf16(a, bv3, acc3, 0, 0, 0); }

#define STORE_H(ACC, NT, DST, STRIDE, BS) if (rb < nv) { \
    int n = (w << 6) + ((NT) << 4) + lane15; \
    float bb = BS[n]; \
    DST[(rb + 0) * STRIDE + n] = __float2bfloat16(ftanh(ACC[0] + bb)); \
    DST[(rb + 1) * STRIDE + n] = __float2bfloat16(ftanh(ACC[1] + bb)); \
    DST[(rb + 2) * STRIDE + n] = __float2bfloat16(ftanh(ACC[2] + bb)); \
    DST[(rb + 3) * STRIDE + n] = __float2bfloat16(ftanh(ACC[3] + bb)); }

    #pragma unroll 2
    for (int ks = 0; ks < 11; ++ks) KSTEP(Dld, 360, ks)
    STORE_H(acc0, 0, Hld, 264, b1s)
    STORE_H(acc1, 1, Hld, 264, b1s)
    STORE_H(acc2, 2, Hld, 264, b1s)
    STORE_H(acc3, 3, Hld, 264, b1s)
    __syncthreads();

    acc0 = (f32x4){0,0,0,0}; acc1 = acc0; acc2 = acc0; acc3 = acc0;
    #pragma unroll 2
    for (int ks = 0; ks < 8; ++ks) KSTEP(Hld, 264, 11 + ks)
    __syncthreads();
    STORE_H(acc0, 0, Dld, 360, b2s)
    STORE_H(acc1, 1, Dld, 360, b2s)
    STORE_H(acc2, 2, Dld, 360, b2s)
    STORE_H(acc3, 3, Dld, 360, b2s)
    __syncthreads();

    acc0 = (f32x4){0,0,0,0}; acc1 = acc0; acc2 = acc0; acc3 = acc0;
    #pragma unroll 2
    for (int ks = 0; ks < 8; ++ks) KSTEP(Dld, 360, 19 + ks)

    float s0 = 0.f, s1 = 0.f, s2 = 0.f, s3 = 0.f;
#define EPART(ACC, NT) if (rb < nv) { \
    int n = (w << 6) + ((NT) << 4) + lane15; \
    float wv = w4s[n]; float bb = b3s[n]; \
    s0 += ftanh(ACC[0] + bb) * wv; s1 += ftanh(ACC[1] + bb) * wv; \
    s2 += ftanh(ACC[2] + bb) * wv; s3 += ftanh(ACC[3] + bb) * wv; }
    EPART(acc0, 0) EPART(acc1, 1) EPART(acc2, 2) EPART(acc3, 3)

    #pragma unroll
    for (int off = 1; off <= 8; off <<= 1) {
        s0 += __shfl_xor(s0, off);
        s1 += __shfl_xor(s1, off);
        s2 += __shfl_xor(s2, off);
        s3 += __shfl_xor(s3, off);
    }
    if (lane15 == 0) {
        red[w][rb + 0] = s0;
        red[w][rb + 1] = s1;
        red[w][rb + 2] = s2;
        red[w][rb + 3] = s3;
    }
    __syncthreads();

    if (tid < 16) {
        float e = red[0][tid] + red[1][tid] + red[2][tid] + red[3][tid];
        e = (tid < nv) ? (e + b4[t]) : 0.0f;
        #pragma unroll
        for (int off = 1; off <= 8; off <<= 1) e += __shfl_xor(e, off);
        if (tid == 0) atomicAdd(out, e);
    }
#undef KSTEP
#undef STORE_H
#undef EPART
}

extern "C" void kernel_launch(void* const* d_in, const int* in_sizes, int n_in,
                              void* d_out, int out_size, void* d_ws, size_t ws_size,
                              hipStream_t stream) {
    const float* xyz   = (const float*)d_in[0];
    const float* box   = (const float*)d_in[1];
    const int*   types = (const int*)  d_in[2];
    const float* w1 = (const float*)d_in[3];
    const float* b1 = (const float*)d_in[4];
    const float* w2 = (const float*)d_in[5];
    const float* b2 = (const float*)d_in[6];
    const float* w3 = (const float*)d_in[7];
    const float* b3 = (const float*)d_in[8];
    const float* w4 = (const float*)d_in[9];
    const float* b4 = (const float*)d_in[10];
    float* out = (float*)d_out;

    // workspace (4B units; 16B alignment preserved at packed/descB)
    float* p = (float*)d_ws;
    int*    histBlk  = (int*)p;        p += 16 * 64;   // fully written by prep
    int*    cnt      = (int*)p;        p += 16;
    int*    slabOffG = (int*)p;        p += 68;
    int*    posArr   = (int*)p;        p += N_ATOMS;
    int*    lists    = (int*)p;        p += 2 * N_ATOMS;
    p += 4;                                             // pad to 16B
    float4* packed   = (float4*)p;     p += 2 * PSTRIDE * 4;
    float*  lfD      = p;              p += 4 * N_ATOMS;
    int*    lfJ      = (int*)p;        p += 4 * N_ATOMS;
    float*  aX       = p;              p += 96 * N_ATOMS;
    float*  aD       = p;              p += 32 * N_ATOMS;
    __hip_bfloat16* descB = (__hip_bfloat16*)p;         // 2*4096*256 bf16
    p += (size_t)2 * N_ATOMS * 256 / 2;
    __hip_bfloat16* Wp = (__hip_bfloat16*)p;            // 2*27*16*512 bf16
    p += (size_t)2 * KSTEPS_TOTAL * 16 * 512 / 2;

    prep_kernel<<<16 + (2 * 864 * 256) / 256, 256, 0, stream>>>(
        xyz, types, histBlk, out, w1, w2, w3, Wp);
    fill_kernel<<<16, 256, 0, stream>>>(xyz, types, histBlk,
                                        slabOffG, cnt, lists, posArr, packed);
    select_kernel<<<2 * N_ATOMS, 256, 0, stream>>>(
        xyz, box, cnt, packed, slabOffG, types, posArr, descB, aX, aD, lfD, lfJ);
    dim3 g(N_ATOMS / 8, 2);
    mlp_fused_kernel<<<g, 256, 0, stream>>>(cnt, lists, xyz, box, aX, aD, lfD, lfJ,
                                            descB, Wp, b1, b2, b3, w4, b4, out);
}

// Round 18
// 67.671 us; speedup vs baseline: 5.2964x; 1.0389x over previous
//
#include <hip/hip_runtime.h>
#include <hip/hip_bf16.h>

#define N_ATOMS 4096
#define NSLAB 32
#define PSTRIDE 8192   // per-type packed stride (duplicated window)
#define KSTEPS_TOTAL 27
typedef unsigned long long ull;
typedef __attribute__((ext_vector_type(8))) __bf16 bf16x8;
typedef __attribute__((ext_vector_type(4))) float f32x4;
typedef __attribute__((ext_vector_type(8))) unsigned short u16x8;

__device__ __forceinline__ float wrapr(float d, float box, float rbox) {
    return d - box * rintf(d * rbox);
}

__device__ __forceinline__ float ftanh(float x) {
    float t = __expf(2.0f * x);
    return 1.0f - 2.0f * __builtin_amdgcn_rcpf(t + 1.0f);
}

// Single prep dispatch. Blocks 0..15: self-contained slab scatter (each block
// recomputes the full histogram + its prefix -> no cross-dispatch dependency);
// packed written duplicated for wrap-free select windows. Blocks 16..:
// bf16 MFMA B-fragment weight packing.
__global__ __launch_bounds__(256) void fill_kernel(
    const float* __restrict__ xyz, const int* __restrict__ types,
    int* __restrict__ slabOffG, int* __restrict__ cntG,
    int* __restrict__ lists, int* __restrict__ posArr,
    float4* __restrict__ packed, float* __restrict__ out,
    const float* __restrict__ w1, const float* __restrict__ w2,
    const float* __restrict__ w3, __hip_bfloat16* __restrict__ Wp)
{
    const int bid = blockIdx.x;
    const int tid = threadIdx.x;

    if (bid < 16) {
        __shared__ int lhAll[64];
        __shared__ int lhPre[64];
        __shared__ int base[64];
        __shared__ int cur[64];
        __shared__ int cntS[2];

        if (tid < 64) { lhAll[tid] = 0; lhPre[tid] = 0; cur[tid] = 0; }
        __syncthreads();

        const int myBase = bid * 256;
        for (int m = tid; m < N_ATOMS; m += 256) {
            int t = types[m];
            int slab = min(NSLAB - 1, (int)(xyz[3*m+2] * (NSLAB / 40.0f)));
            int ts = t * NSLAB + slab;
            atomicAdd(&lhAll[ts], 1);
            if (m < myBase) atomicAdd(&lhPre[ts], 1);
        }
        __syncthreads();

        if (tid < 64) {
            int tot = lhAll[tid];
            int v = tot;   // segmented 32-wide inclusive scan in one wave
            #pragma unroll
            for (int off = 1; off < 32; off <<= 1) {
                int u = __shfl_up(v, off);
                if ((tid & 31) >= off) v += u;
            }
            base[tid] = v - tot;
            int t = tid >> 5, s = tid & 31;
            if (s == 31) cntS[t] = v;
            if (bid == 0) {
                slabOffG[t * (NSLAB + 1) + s + 1] = v;
                if (s == 0)  slabOffG[t * (NSLAB + 1)] = 0;
                if (s == 31) cntG[t] = v;
            }
        }
        if (bid == 0 && tid == 0) out[0] = 0.0f;
        __syncthreads();

        int i = myBase + tid;
        int t = types[i];
        float z = xyz[3*i+2];
        int slab = min(NSLAB - 1, (int)(z * (NSLAB / 40.0f)));
        int ts = t * NSLAB + slab;
        int idx = base[ts] + lhPre[ts] + atomicAdd(&cur[ts], 1);
        lists[t * N_ATOMS + idx] = i;
        posArr[i] = idx;
        float4 pv = make_float4(xyz[3*i+0], xyz[3*i+1], z,
                                __uint_as_float((unsigned)i));
        packed[t * PSTRIDE + idx] = pv;
        packed[t * PSTRIDE + idx + cntS[t]] = pv;   // duplicate: wrap-free reads
    } else {
        int idx = (bid - 16) * 256 + tid;   // exactly 2*864*256 threads
        int n = idx & 255;
        int k = (idx >> 8) % 864;
        int t = idx / (864 * 256);
        int ksg, kr; float v;
        if (k < 352)      { kr = k;       ksg = kr >> 5;        v = w1[((size_t)t*352 + kr)*256 + n]; }
        else if (k < 608) { kr = k - 352; ksg = 11 + (kr >> 5); v = w2[((size_t)t*256 + kr)*256 + n]; }
        else              { kr = k - 608; ksg = 19 + (kr >> 5); v = w3[((size_t)t*256 + kr)*256 + n]; }
        int l  = (((kr & 31) >> 3) << 4) | (n & 15);
        int e  = kr & 7;
        int nt = n >> 4;
        size_t dst = ((((size_t)t*KSTEPS_TOTAL + ksg)*16 + nt) << 9) + (l << 3) + e;
        Wp[dst] = __float2bfloat16(v);
    }
}

// One block per (atom, type): z-slab window (wrap-free via duplicated packed),
// threshold target ~160 nbrs, bucket histogram + scan + cursor scatter, exact
// within-bucket rank by 43-bit key (d2bits<<12 | j) -> exact sorted top-128.
__global__ __launch_bounds__(256) void select_kernel(
    const float* __restrict__ xyz, const float* __restrict__ box,
    const int* __restrict__ cnt, const float4* __restrict__ packed,
    const int* __restrict__ slabOffG,
    const int* __restrict__ types, const int* __restrict__ posArr,
    __hip_bfloat16* __restrict__ descB, float* __restrict__ aX,
    float* __restrict__ aD, float* __restrict__ lfD, int* __restrict__ lfJ)
{
    __shared__ ull sortedk[512];
    __shared__ int hist[256];
    __shared__ int basev[256];
    __shared__ int wsum[4];

    const int i   = blockIdx.x >> 1;
    const int t   = blockIdx.x & 1;
    const int tid = threadIdx.x;
    const int n   = cnt[t];
    const float bx = box[0], by = box[1], bz = box[2];
    const float rbx = 1.0f/bx, rby = 1.0f/by, rbz = 1.0f/bz;
    const float xi = xyz[3*i+0], yi = xyz[3*i+1], zi = xyz[3*i+2];
    const unsigned ibits = (unsigned)i;
    const float4* pk = packed + t * PSTRIDE;
    const int* soff = slabOffG + t * (NSLAB + 1);

    float T = __powf(38.2f * bx * by * bz / (float)n, 0.6666667f);   // ~160 nbrs
    float Twin = -1.0f, scale = 1.0f;
    int A = 0, L = n;
    int count = 0;
    float d2r[10];

    for (int attempt = 0; attempt < 8; ++attempt) {
        if (T > Twin) {
            float r = sqrtf(T);
            int slo = (int)floorf((zi - r) * (NSLAB / 40.0f)) - 1;
            int shi = (int)floorf((zi + r) * (NSLAB / 40.0f)) + 1;
            int nsl = shi - slo + 1;
            if (nsl >= NSLAB) { A = 0; L = n; }
            else {
                int ss = slo & (NSLAB - 1);
                A = soff[ss];
                int send = ss + nsl;
                L = (send <= NSLAB) ? (soff[send] - A)
                                    : (n - A) + soff[send - NSLAB];
            }
            Twin = T;
            scale = 256.0f / Twin;
            #pragma unroll
            for (int c = 0; c < 10; ++c) {
                d2r[c] = __builtin_inff();
                if ((c << 8) < L) {
                    int m = tid + (c << 8);
                    if (m < L) {
                        float4 p = pk[A + m];           // wrap-free (duplicated)
                        if (__float_as_uint(p.w) != ibits) {
                            float ax_ = fabsf(xi - p.x);
                            float ay_ = fabsf(yi - p.y);
                            float az_ = fabsf(zi - p.z);
                            float mx = fminf(ax_, bx - ax_);
                            float my = fminf(ay_, by - ay_);
                            float mz = fminf(az_, bz - az_);
                            d2r[c] = mx*mx + my*my + mz*mz;
                        }
                    }
                }
            }
        }

        hist[tid] = 0;
        __syncthreads();
        #pragma unroll
        for (int c = 0; c < 10; ++c) {
            if (d2r[c] < T)
                atomicAdd(&hist[min(255, (int)(d2r[c] * scale))], 1);
        }
        __syncthreads();
        int h = hist[tid];
        int v = h;
        #pragma unroll
        for (int off = 1; off < 64; off <<= 1) {
            int u = __shfl_up(v, off);
            if ((tid & 63) >= off) v += u;
        }
        if ((tid & 63) == 63) wsum[tid >> 6] = v;
        __syncthreads();
        int woff = 0;
        #pragma unroll
        for (int w2 = 0; w2 < 3; ++w2) if (w2 < (tid >> 6)) woff += wsum[w2];
        basev[tid] = v + woff - h;     // exclusive start; doubles as cursor
        count = wsum[0] + wsum[1] + wsum[2] + wsum[3];
        __syncthreads();
        if (count >= 128 && count <= 511) break;
        T *= (count < 128) ? 1.9f : 0.6f;
    }

    #pragma unroll
    for (int c = 0; c < 10; ++c) {
        if (d2r[c] < T) {
            int b = min(255, (int)(d2r[c] * scale));
            int pp = atomicAdd(&basev[b], 1);
            if (pp < 512) {
                int m = tid + (c << 8);
                unsigned j = __float_as_uint(pk[A + m].w);
                sortedk[pp] = ((ull)__float_as_uint(d2r[c]) << 12) | j;
            }
        }
    }
    __syncthreads();
    const int cnt2 = min(count, 512);

    const int ti = types[i];
    const int pi = posArr[i];
    __hip_bfloat16* drow = descB + ((size_t)ti * N_ATOMS + pi) * 256;
    for (int s = tid; s < cnt2; s += 256) {
        ull k = sortedk[s];
        float d2 = __uint_as_float((unsigned)(k >> 12));
        int b = min(255, (int)(d2 * scale));
        int hh = hist[b];
        int r = s;
        if (hh > 1) {
            int bs = basev[b] - hh;    // cursor end minus bucket size = start
            int hi2 = min(bs + hh, cnt2);
            r = bs;
            for (int x = bs; x < hi2; ++x) r += (sortedk[x] < k) ? 1 : 0;
        }
        if (r < 128) {
            int j = (int)(k & 0xFFF);
            float dist = sqrtf(d2);
            drow[t * 128 + r] = __float2bfloat16(1.0f / (dist + 1e-16f));
            if (r < 16) {
                float dx = wrapr(xi - xyz[3*j+0], bx, rbx);
                float dy = wrapr(yi - xyz[3*j+1], by, rby);
                float dz = wrapr(zi - xyz[3*j+2], bz, rbz);
                int s2 = i * 32 + t * 16 + r;
                aX[3*s2+0] = dx; aX[3*s2+1] = dy; aX[3*s2+2] = dz;
                aD[s2] = dist;
            }
            if (r < 2) {
                lfD[i * 4 + t * 2 + r] = dist;
                lfJ[i * 4 + t * 2 + r] = j;
            }
        }
    }
}

// Fused: local frame + rot features + 3-layer bf16-MFMA MLP + energy.
// Block = 8 atoms x 256 neurons, 4 waves. C/D: col=lane&15, row=(lane>>4)*4+reg.
__global__ __launch_bounds__(256) void mlp_fused_kernel(
    const int* __restrict__ cnt, const int* __restrict__ lists,
    const float* __restrict__ xyz, const float* __restrict__ box,
    const float* __restrict__ aX, const float* __restrict__ aD,
    const float* __restrict__ lfD, const int* __restrict__ lfJ,
    const __hip_bfloat16* __restrict__ descB,
    const __hip_bfloat16* __restrict__ Wp,
    const float* __restrict__ b1, const float* __restrict__ b2,
    const float* __restrict__ b3,
    const float* __restrict__ w4, const float* __restrict__ b4,
    float* __restrict__ out)
{
    __shared__ __hip_bfloat16 Dld[16 * 360];
    __shared__ __hip_bfloat16 Hld[16 * 264];
    __shared__ float b1s[256], b2s[256], b3s[256], w4s[256];
    __shared__ float red[4][16];
    __shared__ float Am[8][12];
    __shared__ int atoms[8];

    const int t   = blockIdx.y;
    const int n_t = cnt[t];
    const int p0  = blockIdx.x * 8;
    if (p0 >= n_t) return;
    const int nv  = min(8, n_t - p0);
    const int tid = threadIdx.x;
    const int w   = tid >> 6;
    const int l   = tid & 63;
    const int lane15 = l & 15;
    const float bx = box[0], by = box[1], bz = box[2];
    const float rbx = 1.0f/bx, rby = 1.0f/by, rbz = 1.0f/bz;

    b1s[tid] = b1[t * 256 + tid];
    b2s[tid] = b2[t * 256 + tid];
    b3s[tid] = b3[t * 256 + tid];
    w4s[tid] = w4[t * 256 + tid];
    if (tid < 8)
        atoms[tid] = (tid < nv) ? lists[t * N_ATOMS + p0 + tid] : -1;

    for (int c = tid; c < 16 * 44; c += 256) {
        int row = c / 44, kc = c - row * 44;
        u16x8 v = {0,0,0,0,0,0,0,0};
        if (row < nv && kc < 32)
            v = *(const u16x8*)&descB[((size_t)t*N_ATOMS + p0 + row)*256 + kc*8];
        *(u16x8*)&Dld[row * 360 + kc * 8] = v;
    }
    __syncthreads();

    if (tid < 8 && atoms[tid] >= 0) {
        const int a = atoms[tid];
        const float xi = xyz[3*a+0], yi = xyz[3*a+1], zi = xyz[3*a+2];
        float cd[4]; int cj[4];
        #pragma unroll
        for (int c = 0; c < 4; ++c) { cd[c] = lfD[a*4+c]; cj[c] = lfJ[a*4+c]; }
        int i0 = 0; float bm = cd[0];
        for (int c = 1; c < 4; ++c) if (cd[c] < bm) { bm = cd[c]; i0 = c; }
        int i1 = -1; float b1v = 3.4e38f;
        for (int c = 0; c < 4; ++c) { if (c == i0) continue; if (cd[c] < b1v) { b1v = cd[c]; i1 = c; } }

        int ja = cj[i0], jb = cj[i1];
        float da = cd[i0], db = cd[i1];
        float r0x = wrapr(xi - xyz[3*ja+0], bx, rbx) / (da + 1e-16f);
        float r0y = wrapr(yi - xyz[3*ja+1], by, rby) / (da + 1e-16f);
        float r0z = wrapr(zi - xyz[3*ja+2], bz, rbz) / (da + 1e-16f);
        float r1x = wrapr(xi - xyz[3*jb+0], bx, rbx) / (db + 1e-16f);
        float r1y = wrapr(yi - xyz[3*jb+1], by, rby) / (db + 1e-16f);
        float r1z = wrapr(zi - xyz[3*jb+2], bz, rbz) / (db + 1e-16f);
        float dot = r0x*r1x + r0y*r1y + r0z*r1z;
        float v2x = r1x - dot*r0x, v2y = r1y - dot*r0y, v2z = r1z - dot*r0z;
        float n2 = sqrtf(v2x*v2x + v2y*v2y + v2z*v2z);
        v2x /= n2; v2y /= n2; v2z /= n2;
        float v3x = r0y*r1z - r0z*r1y;
        float v3y = r0z*r1x - r0x*r1z;
        float v3z = r0x*r1y - r0y*r1x;
        float n3 = sqrtf(v3x*v3x + v3y*v3y + v3z*v3z);
        v3x /= n3; v3y /= n3; v3z /= n3;
        Am[tid][0]=r0x; Am[tid][1]=r0y; Am[tid][2]=r0z;
        Am[tid][3]=v2x; Am[tid][4]=v2y; Am[tid][5]=v2z;
        Am[tid][6]=v3x; Am[tid][7]=v3y; Am[tid][8]=v3z;
    }
    __syncthreads();

    if (tid < 128) {
        const int q = tid >> 4, s = tid & 15;
        const int a = atoms[q];
        if (a >= 0) {
            #pragma unroll
            for (int half = 0; half < 2; ++half) {
                int ss = s + (half << 4);
                int sidx = a * 32 + ss;
                float d  = aD[sidx];
                float dn = d + 1e-16f;
                float ax = aX[3*sidx+0] / dn;
                float ay = aX[3*sidx+1] / dn;
                float az = aX[3*sidx+2] / dn;
                float o0 = (Am[q][0]*ax + Am[q][1]*ay + Am[q][2]*az) / dn;
                float o1 = (Am[q][3]*ax + Am[q][4]*ay + Am[q][5]*az) / dn;
                float o2 = (Am[q][6]*ax + Am[q][7]*ay + Am[q][8]*az) / dn;
                Dld[q*360 + 256 + 3*ss + 0] = __float2bfloat16(o0);
                Dld[q*360 + 256 + 3*ss + 1] = __float2bfloat16(o1);
                Dld[q*360 + 256 + 3*ss + 2] = __float2bfloat16(o2);
            }
        }
    }
    __syncthreads();

    const __hip_bfloat16* wpt = Wp + (((size_t)t * KSTEPS_TOTAL * 16 + (w << 2)) << 9);
    const int aoff = ((l >> 4) << 3);
    const int rb   = ((l >> 4) << 2);

    f32x4 acc0 = {0,0,0,0}, acc1 = {0,0,0,0}, acc2 = {0,0,0,0}, acc3 = {0,0,0,0};

#define KSTEP(SRC, STRIDE, KSG) { \
    bf16x8 a = *(const bf16x8*)&SRC[lane15 * STRIDE + (ks << 5) + aoff]; \
    const __hip_bfloat16* wk = wpt + (((size_t)(KSG) << 13)) + (l << 3); \
    bf16x8 bv0 = *(const bf16x8*)(wk); \
    bf16x8 bv1 = *(const bf16x8*)(wk + 512); \
    bf16x8 bv2 = *(const bf16x8*)(wk + 1024); \
    bf16x8 bv3 = *(const bf16x8*)(wk + 1536); \
    acc0 = __builtin_amdgcn_mfma_f32_16x16x32_bf16(a, bv0, acc0, 0, 0, 0); \
    acc1 = __builtin_amdgcn_mfma_f32_16x16x32_bf16(a, bv1, acc1, 0, 0, 0); \
    acc2 = __builtin_amdgcn_mfma_f32_16x16x32_bf16(a, bv2, acc2, 0, 0, 0); \
    acc3 = __builtin_amdgcn_mfma_f32_16x16x32_bf16(a, bv3, acc3, 0, 0, 0); }

#define STORE_H(ACC, NT, DST, STRIDE, BS) if (rb < nv) { \
    int n = (w << 6) + ((NT) << 4) + lane15; \
    float bb = BS[n]; \
    DST[(rb + 0) * STRIDE + n] = __float2bfloat16(ftanh(ACC[0] + bb)); \
    DST[(rb + 1) * STRIDE + n] = __float2bfloat16(ftanh(ACC[1] + bb)); \
    DST[(rb + 2) * STRIDE + n] = __float2bfloat16(ftanh(ACC[2] + bb)); \
    DST[(rb + 3) * STRIDE + n] = __float2bfloat16(ftanh(ACC[3] + bb)); }

    #pragma unroll 2
    for (int ks = 0; ks < 11; ++ks) KSTEP(Dld, 360, ks)
    STORE_H(acc0, 0, Hld, 264, b1s)
    STORE_H(acc1, 1, Hld, 264, b1s)
    STORE_H(acc2, 2, Hld, 264, b1s)
    STORE_H(acc3, 3, Hld, 264, b1s)
    __syncthreads();

    acc0 = (f32x4){0,0,0,0}; acc1 = acc0; acc2 = acc0; acc3 = acc0;
    #pragma unroll 2
    for (int ks = 0; ks < 8; ++ks) KSTEP(Hld, 264, 11 + ks)
    __syncthreads();
    STORE_H(acc0, 0, Dld, 360, b2s)
    STORE_H(acc1, 1, Dld, 360, b2s)
    STORE_H(acc2, 2, Dld, 360, b2s)
    STORE_H(acc3, 3, Dld, 360, b2s)
    __syncthreads();

    acc0 = (f32x4){0,0,0,0}; acc1 = acc0; acc2 = acc0; acc3 = acc0;
    #pragma unroll 2
    for (int ks = 0; ks < 8; ++ks) KSTEP(Dld, 360, 19 + ks)

    float s0 = 0.f, s1 = 0.f, s2 = 0.f, s3 = 0.f;
#define EPART(ACC, NT) if (rb < nv) { \
    int n = (w << 6) + ((NT) << 4) + lane15; \
    float wv = w4s[n]; float bb = b3s[n]; \
    s0 += ftanh(ACC[0] + bb) * wv; s1 += ftanh(ACC[1] + bb) * wv; \
    s2 += ftanh(ACC[2] + bb) * wv; s3 += ftanh(ACC[3] + bb) * wv; }
    EPART(acc0, 0) EPART(acc1, 1) EPART(acc2, 2) EPART(acc3, 3)

    #pragma unroll
    for (int off = 1; off <= 8; off <<= 1) {
        s0 += __shfl_xor(s0, off);
        s1 += __shfl_xor(s1, off);
        s2 += __shfl_xor(s2, off);
        s3 += __shfl_xor(s3, off);
    }
    if (lane15 == 0) {
        red[w][rb + 0] = s0;
        red[w][rb + 1] = s1;
        red[w][rb + 2] = s2;
        red[w][rb + 3] = s3;
    }
    __syncthreads();

    if (tid < 16) {
        float e = red[0][tid] + red[1][tid] + red[2][tid] + red[3][tid];
        e = (tid < nv) ? (e + b4[t]) : 0.0f;
        #pragma unroll
        for (int off = 1; off <= 8; off <<= 1) e += __shfl_xor(e, off);
        if (tid == 0) atomicAdd(out, e);
    }
#undef KSTEP
#undef STORE_H
#undef EPART
}

extern "C" void kernel_launch(void* const* d_in, const int* in_sizes, int n_in,
                              void* d_out, int out_size, void* d_ws, size_t ws_size,
                              hipStream_t stream) {
    const float* xyz   = (const float*)d_in[0];
    const float* box   = (const float*)d_in[1];
    const int*   types = (const int*)  d_in[2];
    const float* w1 = (const float*)d_in[3];
    const float* b1 = (const float*)d_in[4];
    const float* w2 = (const float*)d_in[5];
    const float* b2 = (const float*)d_in[6];
    const float* w3 = (const float*)d_in[7];
    const float* b3 = (const float*)d_in[8];
    const float* w4 = (const float*)d_in[9];
    const float* b4 = (const float*)d_in[10];
    float* out = (float*)d_out;

    // workspace (4B units; 16B alignment preserved at packed/descB)
    float* p = (float*)d_ws;
    int*    cnt      = (int*)p;        p += 16;
    int*    slabOffG = (int*)p;        p += 68;
    int*    posArr   = (int*)p;        p += N_ATOMS;
    int*    lists    = (int*)p;        p += 2 * N_ATOMS;
    p += 12;                                            // pad to 16B
    float4* packed   = (float4*)p;     p += 2 * PSTRIDE * 4;
    float*  lfD      = p;              p += 4 * N_ATOMS;
    int*    lfJ      = (int*)p;        p += 4 * N_ATOMS;
    float*  aX       = p;              p += 96 * N_ATOMS;
    float*  aD       = p;              p += 32 * N_ATOMS;
    __hip_bfloat16* descB = (__hip_bfloat16*)p;         // 2*4096*256 bf16
    p += (size_t)2 * N_ATOMS * 256 / 2;
    __hip_bfloat16* Wp = (__hip_bfloat16*)p;            // 2*27*16*512 bf16
    p += (size_t)2 * KSTEPS_TOTAL * 16 * 512 / 2;

    fill_kernel<<<16 + (2 * 864 * 256) / 256, 256, 0, stream>>>(
        xyz, types, slabOffG, cnt, lists, posArr, packed, out, w1, w2, w3, Wp);
    select_kernel<<<2 * N_ATOMS, 256, 0, stream>>>(
        xyz, box, cnt, packed, slabOffG, types, posArr, descB, aX, aD, lfD, lfJ);
    dim3 g(N_ATOMS / 8, 2);
    mlp_fused_kernel<<<g, 256, 0, stream>>>(cnt, lists, xyz, box, aX, aD, lfD, lfJ,
                                            descB, Wp, b1, b2, b3, w4, b4, out);
}